// Round 5
// baseline (642.056 us; speedup 1.0000x reference)
//
#include <hip/hip_runtime.h>
#include <hip/hip_bf16.h>

#define NN 50000
#define NE 1600000
#define DD 128

__device__ __forceinline__ float bf2f(unsigned short u) {
    union { unsigned int i; float f; } c; c.i = ((unsigned int)u) << 16; return c.f;
}
__device__ __forceinline__ unsigned short f2bf(float f) {
    __hip_bfloat16 h = __float2bfloat16(f);
    union { __hip_bfloat16 h; unsigned short u; } c; c.h = h; return c.u;
}
__device__ __forceinline__ int insane_bf16(unsigned short u) {
    unsigned e = (u >> 7) & 0xFF;
    return (e == 0xFF) || (e >= 0x8E);
}

// flags[0]=indices int64; flags[1]=feat f32 (=> out f32); flags[2]=W f32
__global__ void k_detect(const int* __restrict__ srcw, const int* __restrict__ dstw,
                         const unsigned short* __restrict__ feat16,
                         const unsigned short* __restrict__ w16,
                         int* __restrict__ flags) {
    __shared__ int s_idx, s_feat, s_w;
    int tid = threadIdx.x;
    if (tid == 0) { s_idx = 0; s_feat = 0; s_w = 0; }
    __syncthreads();
    if (tid < 64) {
        int v = srcw[2 * tid + 1] | dstw[2 * tid + 1];
        if (v) atomicOr(&s_idx, 1);
    }
    if (insane_bf16(feat16[2 * tid]) || insane_bf16(feat16[2 * tid + 512]))
        atomicOr(&s_feat, 1);
    if (insane_bf16(w16[2 * tid]) || insane_bf16(w16[2 * tid + 512]))
        atomicOr(&s_w, 1);
    __syncthreads();
    if (tid == 0) { flags[0] = (s_idx == 0) ? 1 : 0; flags[1] = s_feat; flags[2] = s_w; }
}

__device__ __forceinline__ int load_idx(const void* p, int e, int is64) {
    long long v = is64 ? ((const long long*)p)[e] : (long long)((const int*)p)[e];
    int i = (int)v;
    return (i < 0) ? 0 : (i >= NN ? NN - 1 : i);
}

__global__ void k_zero(int* __restrict__ deg) {
    int i = blockIdx.x * 256 + threadIdx.x;
    if (i < NN) deg[i] = 0;
}

__global__ void k_degree(const void* __restrict__ dst, int* __restrict__ deg,
                         const int* __restrict__ flags) {
    int e = blockIdx.x * 256 + threadIdx.x;
    if (e >= NE) return;
    atomicAdd(&deg[load_idx(dst, e, flags[0])], 1);
}

// fused: exclusive scan -> rowptr + cursor copy, and norm = rsqrt(clip(deg,1))
#define CH 49   // ceil(50000/1024)
__global__ __launch_bounds__(1024) void k_scan(const int* __restrict__ deg,
        int* __restrict__ rowptr, int* __restrict__ cur, float* __restrict__ norm) {
    __shared__ int part[1024];
    int tid = threadIdx.x;
    int base = tid * CH;
    int s = 0;
    for (int k = 0; k < CH; ++k) {
        int i = base + k;
        if (i < NN) s += deg[i];
    }
    part[tid] = s;
    __syncthreads();
    for (int off = 1; off < 1024; off <<= 1) {
        int t = (tid >= off) ? part[tid - off] : 0;
        __syncthreads();
        part[tid] += t;
        __syncthreads();
    }
    int running = part[tid] - s;   // exclusive prefix of this thread's chunk
    for (int k = 0; k < CH; ++k) {
        int i = base + k;
        if (i < NN) {
            int d = deg[i];
            rowptr[i] = running;
            cur[i] = running;
            norm[i] = rsqrtf(fmaxf((float)d, 1.0f));
            running += d;
        }
    }
    if (tid == 1023) rowptr[NN] = part[1023];
}

// fill CSR: srclist[cur[d]++] = src
__global__ void k_bucket(const void* __restrict__ src, const void* __restrict__ dst,
                         int* __restrict__ cur, int* __restrict__ srclist,
                         const int* __restrict__ flags) {
    int e = blockIdx.x * 256 + threadIdx.x;
    if (e >= NE) return;
    int is64 = flags[0];
    int s = load_idx(src, e, is64);
    int d = load_idx(dst, e, is64);
    int pos = atomicAdd(&cur[d], 1);
    srclist[pos] = s;
}

// X1[n,d] = feat[n,d] * norm[n]  (bf16), 4 elems/thread
__global__ void k_prescale(const void* __restrict__ feat,
                           const float* __restrict__ norm,
                           unsigned short* __restrict__ X,
                           const int* __restrict__ flags) {
    int i = blockIdx.x * 256 + threadIdx.x;
    if (i >= NN * DD / 4) return;
    float nm = norm[i >> 5];
    float4 v;
    if (flags[1]) {
        v = ((const float4*)feat)[i];
    } else {
        ushort4 f = ((const ushort4*)feat)[i];
        v.x = bf2f(f.x); v.y = bf2f(f.y); v.z = bf2f(f.z); v.w = bf2f(f.w);
    }
    ushort4 o;
    o.x = f2bf(v.x * nm); o.y = f2bf(v.y * nm);
    o.z = f2bf(v.z * nm); o.w = f2bf(v.w * nm);
    ((ushort4*)X)[i] = o;
}

__device__ __forceinline__ void acc8(float* a, uint4 v) {
    a[0] += bf2f((unsigned short)(v.x & 0xffff));
    a[1] += bf2f((unsigned short)(v.x >> 16));
    a[2] += bf2f((unsigned short)(v.y & 0xffff));
    a[3] += bf2f((unsigned short)(v.y >> 16));
    a[4] += bf2f((unsigned short)(v.z & 0xffff));
    a[5] += bf2f((unsigned short)(v.z >> 16));
    a[6] += bf2f((unsigned short)(v.w & 0xffff));
    a[7] += bf2f((unsigned short)(v.w >> 16));
}

// gather-reduce: one wave per dst node; 4 edge-slots x 16 lanes x 16B rows.
// mode 0: out = bf16(acc * norm[n]^2) -> X2;  mode 1: out = acc (f32/bf16) -> d_out
__global__ __launch_bounds__(256) void k_gather(const unsigned short* __restrict__ Xin,
        const int* __restrict__ rowptr, const int* __restrict__ srclist,
        const float* __restrict__ norm, void* __restrict__ outp,
        const int* __restrict__ flags, int mode) {
    int wid = (blockIdx.x * 256 + threadIdx.x) >> 6;
    int lane = threadIdx.x & 63;
    if (wid >= NN) return;
    int beg = rowptr[wid], end = rowptr[wid + 1];
    int g = lane >> 4;                 // edge slot 0..3
    int c8 = (lane & 15) << 3;         // col base (elements)
    const unsigned short* xb = Xin + c8;
    float a[8];
    #pragma unroll
    for (int k = 0; k < 8; ++k) a[k] = 0.f;

    for (int j = beg + g; j < end; j += 8) {
        int s0 = srclist[j];
        uint4 v0 = *(const uint4*)(xb + s0 * DD);
        int j2 = j + 4;
        if (j2 < end) {
            int s1 = srclist[j2];
            uint4 v1 = *(const uint4*)(xb + s1 * DD);
            acc8(a, v0);
            acc8(a, v1);
        } else {
            acc8(a, v0);
        }
    }
    // merge the 4 edge slots: butterfly over lane^16, lane^32
    #pragma unroll
    for (int k = 0; k < 8; ++k) {
        a[k] += __shfl_xor(a[k], 16);
        a[k] += __shfl_xor(a[k], 32);
    }

    if (mode == 0) {
        if (g == 0) {
            float nm = norm[wid]; float n2 = nm * nm;
            uint4 o;
            o.x = ((unsigned)f2bf(a[1] * n2) << 16) | (unsigned)f2bf(a[0] * n2);
            o.y = ((unsigned)f2bf(a[3] * n2) << 16) | (unsigned)f2bf(a[2] * n2);
            o.z = ((unsigned)f2bf(a[5] * n2) << 16) | (unsigned)f2bf(a[4] * n2);
            o.w = ((unsigned)f2bf(a[7] * n2) << 16) | (unsigned)f2bf(a[6] * n2);
            *(uint4*)((unsigned short*)outp + wid * DD + c8) = o;
        }
    } else if (flags[1]) {
        if (g == 0)
            *(float4*)((float*)outp + wid * DD + c8) = make_float4(a[0], a[1], a[2], a[3]);
        else if (g == 1)
            *(float4*)((float*)outp + wid * DD + c8 + 4) = make_float4(a[4], a[5], a[6], a[7]);
    } else {
        if (g == 0) {
            uint4 o;
            o.x = ((unsigned)f2bf(a[1]) << 16) | (unsigned)f2bf(a[0]);
            o.y = ((unsigned)f2bf(a[3]) << 16) | (unsigned)f2bf(a[2]);
            o.z = ((unsigned)f2bf(a[5]) << 16) | (unsigned)f2bf(a[4]);
            o.w = ((unsigned)f2bf(a[7]) << 16) | (unsigned)f2bf(a[6]);
            *(uint4*)((unsigned short*)outp + wid * DD + c8) = o;
        }
    }
}

// In-place GEMM on d_out: out[n,:] = (Y[n,:]*norm[n]) @ W^T + b
__global__ __launch_bounds__(256) void k_gemm(void* __restrict__ Yio,
        const float* __restrict__ norm, const void* __restrict__ Wp,
        const void* __restrict__ bp, const int* __restrict__ flags) {
    __shared__ unsigned int uw[DD * 65];     // 33,280 B
    __shared__ float Fl[32 * 130];           // 16,640 B
    int tid = threadIdx.x;
    int nodeBase = blockIdx.x * 32;
    int wf32 = flags[2];
    int of32 = flags[1];

    for (int idx = tid; idx < DD * 64; idx += 256) {
        int o = idx >> 6, kk = idx & 63;
        unsigned pk;
        if (wf32) {
            float2 w = ((const float2*)Wp)[o * 64 + kk];
            pk = ((unsigned)f2bf(w.y) << 16) | (unsigned)f2bf(w.x);
        } else {
            pk = ((const unsigned*)Wp)[o * 64 + kk];
        }
        uw[o * 65 + kk] = pk;
    }
    for (int idx = tid; idx < 32 * DD; idx += 256) {
        int nl = idx >> 7, d = idx & 127;
        int n = nodeBase + nl;
        float v = 0.0f;
        if (n < NN) {
            float nm = norm[n];
            v = of32 ? ((const float*)Yio)[n * DD + d] * nm
                     : bf2f(((const unsigned short*)Yio)[n * DD + d]) * nm;
        }
        Fl[nl * 130 + d] = v;
    }
    __syncthreads();

    int og = tid & 15;
    int ng = tid >> 4;
    int nl0 = ng * 2;
    float acc0[8], acc1[8];
    #pragma unroll
    for (int j = 0; j < 8; ++j) { acc0[j] = 0.f; acc1[j] = 0.f; }
    const float* r0 = &Fl[nl0 * 130];
    const float* r1 = &Fl[(nl0 + 1) * 130];
    #pragma unroll 4
    for (int kk = 0; kk < 64; ++kk) {
        float2 f0 = *(const float2*)(r0 + 2 * kk);
        float2 f1 = *(const float2*)(r1 + 2 * kk);
        #pragma unroll
        for (int j = 0; j < 8; ++j) {
            unsigned w = uw[(og + 16 * j) * 65 + kk];
            float w0 = bf2f((unsigned short)(w & 0xffff));
            float w1 = bf2f((unsigned short)(w >> 16));
            acc0[j] += f0.x * w0 + f0.y * w1;
            acc1[j] += f1.x * w0 + f1.y * w1;
        }
    }
    int n0 = nodeBase + nl0;
    #pragma unroll
    for (int j = 0; j < 8; ++j) {
        int o = og + 16 * j;
        float bias = wf32 ? ((const float*)bp)[o] : bf2f(((const unsigned short*)bp)[o]);
        float v0 = acc0[j] + bias, v1 = acc1[j] + bias;
        if (of32) {
            float* out = (float*)Yio;
            if (n0 < NN)     out[n0 * DD + o] = v0;
            if (n0 + 1 < NN) out[(n0 + 1) * DD + o] = v1;
        } else {
            unsigned short* out = (unsigned short*)Yio;
            if (n0 < NN)     out[n0 * DD + o] = f2bf(v0);
            if (n0 + 1 < NN) out[(n0 + 1) * DD + o] = f2bf(v1);
        }
    }
}

extern "C" void kernel_launch(void* const* d_in, const int* in_sizes, int n_in,
                              void* d_out, int out_size, void* d_ws, size_t ws_size,
                              hipStream_t stream) {
    const void* feat = d_in[0];
    const void* src  = d_in[1];
    const void* dst  = d_in[2];
    const void* W    = d_in[3];
    const void* b    = d_in[4];

    // ws (bytes): flags@0 | deg@32 | rowptr@200032 | cur@400064 | norm@600064 |
    //             srclist@800064 | X1@7200064 | X2@20000064   (end 32.8MB)
    char* wsb = (char*)d_ws;
    int*   flags   = (int*)wsb;
    int*   deg     = (int*)(wsb + 32);
    int*   rowptr  = (int*)(wsb + 200032);
    int*   cur     = (int*)(wsb + 400064);
    float* norm    = (float*)(wsb + 600064);
    int*   srclist = (int*)(wsb + 800064);
    unsigned short* X1 = (unsigned short*)(wsb + 7200064);
    unsigned short* X2 = (unsigned short*)(wsb + 20000064);

    k_detect<<<1, 256, 0, stream>>>((const int*)src, (const int*)dst,
                                    (const unsigned short*)feat,
                                    (const unsigned short*)W, flags);
    k_zero<<<(NN + 255) / 256, 256, 0, stream>>>(deg);
    k_degree<<<(NE + 255) / 256, 256, 0, stream>>>(dst, deg, flags);
    k_scan<<<1, 1024, 0, stream>>>(deg, rowptr, cur, norm);
    k_bucket<<<(NE + 255) / 256, 256, 0, stream>>>(src, dst, cur, srclist, flags);
    k_prescale<<<(NN * DD / 4 + 255) / 256, 256, 0, stream>>>(feat, norm, X1, flags);
    k_gather<<<(NN + 3) / 4, 256, 0, stream>>>(X1, rowptr, srclist, norm, X2, flags, 0);
    k_gather<<<(NN + 3) / 4, 256, 0, stream>>>(X2, rowptr, srclist, norm, d_out, flags, 1);
    k_gemm<<<(NN + 31) / 32, 256, 0, stream>>>(d_out, norm, W, b, flags);
}